// Round 8
// baseline (485.104 us; speedup 1.0000x reference)
//
#include <hip/hip_runtime.h>
#include <cstdint>
#include <cstddef>

// Problem constants: B=16, T=4096, D_IN=H=512, L=2, 3H=1536
#define BB 16
#define TT 4096
#define DD 512
#define NG 1536
#define NCH 64            // chunks per chain
#define CS  (TT / NCH)    // 64 timesteps per chunk
#define NCHAIN (BB * DD)  // 8192 chains

typedef __bf16 bf16x8 __attribute__((ext_vector_type(8)));
typedef float f32x4 __attribute__((ext_vector_type(4)));
typedef unsigned short u16;
typedef __attribute__((ext_vector_type(4))) unsigned short u16x4;

__device__ __forceinline__ u16 f2bf(float f) {
  union { float f; unsigned u; } v; v.f = f;
  return (u16)((v.u + 0x7FFFu + ((v.u >> 16) & 1u)) >> 16);
}
__device__ __forceinline__ float bf2f(u16 s) {
  union { unsigned u; float f; } v; v.u = ((unsigned)s) << 16;
  return v.f;
}
__device__ __forceinline__ float sigm(float x) {
  return 1.f / (1.f + __expf(-x));
}
// RNE f32x2 -> packed bf16x2 (matches f2bf on normal values)
__device__ __forceinline__ unsigned cvtpk_bf16(float lo, float hi) {
  unsigned r;
  asm("v_cvt_pk_bf16_f32 %0, %1, %2" : "=v"(r) : "v"(lo), "v"(hi));
  return r;
}

// async global->LDS, 16B per lane. LDS dest = wave-uniform base + lane*16.
__device__ __forceinline__ void gload_lds16(const void* g, void* l) {
  __builtin_amdgcn_global_load_lds(
      (const __attribute__((address_space(1))) unsigned*)g,
      (__attribute__((address_space(3))) unsigned*)l, 16, 0, 0);
}

#define BAR() __builtin_amdgcn_s_barrier()

// ---------------------------------------------------------------------------
// fp32 -> bf16 bulk convert (now only used for W0/W1: 1.5 MB each)
// ---------------------------------------------------------------------------
__global__ __launch_bounds__(256) void f32_to_bf16(
    const float* __restrict__ in, u16* __restrict__ out, long n)
{
  const long stride = (long)gridDim.x * 256 * 8;
  for (long i = ((long)blockIdx.x * 256 + threadIdx.x) * 8; i < n; i += stride) {
    float4 a = *reinterpret_cast<const float4*>(in + i);
    float4 b = *reinterpret_cast<const float4*>(in + i + 4);
    uint4 p;
    p.x = (unsigned)f2bf(a.x) | ((unsigned)f2bf(a.y) << 16);
    p.y = (unsigned)f2bf(a.z) | ((unsigned)f2bf(a.w) << 16);
    p.z = (unsigned)f2bf(b.x) | ((unsigned)f2bf(b.y) << 16);
    p.w = (unsigned)f2bf(b.z) | ((unsigned)f2bf(b.w) << 16);
    *reinterpret_cast<uint4*>(out + i) = p;
  }
}

// ---------------------------------------------------------------------------
// Shared GEMM epilogue: LDS bounce (EPS=280), coalesced 16B/lane stores.
// Validated in R5/R7 (WRITE_SIZE == 196.6 MB ideal).
// ---------------------------------------------------------------------------
__device__ __forceinline__ void gemm_epilogue(
    u16* ep, const f32x4 (&acc)[4][4], const float* __restrict__ bias,
    long mRow0, int nRow0, int tid, int wm, int wn, int laneM, int laneHi,
    u16* __restrict__ out)
{
  float bvv[4];
#pragma unroll
  for (int ni = 0; ni < 4; ++ni)
    bvv[ni] = bias[nRow0 + wn * 64 + ni * 16 + laneM];
#pragma unroll
  for (int mi = 0; mi < 4; ++mi)
#pragma unroll
    for (int ni = 0; ni < 4; ++ni)
#pragma unroll
      for (int r = 0; r < 4; ++r)
        ep[(wm * 64 + mi * 16 + laneHi * 4 + r) * 280 +
           wn * 64 + ni * 16 + laneM] = f2bf(acc[mi][ni][r] + bvv[ni]);
  asm volatile("s_waitcnt lgkmcnt(0)" ::: "memory");
  __builtin_amdgcn_sched_barrier(0);
  BAR();
#pragma unroll
  for (int it = 0; it < 8; ++it) {
    const int row = tid >> 2;                       // 0..127
    const int col = ((tid & 3) + it * 4) * 8;       // 0..248 (u16)
    uint4 v = *reinterpret_cast<const uint4*>(&ep[row * 280 + col]);
    *reinterpret_cast<uint4*>(
        &out[(mRow0 + row) * (long)NG + nRow0 + col]) = v;
  }
}

// ---------------------------------------------------------------------------
// Layer-0 GEMM: A is fp32 (x read directly -> kills the 201 MB convert
// round-trip). 128x256 tile, BK=32, 8 waves of 64x64, double-buffered,
// depth-1 counted vmcnt(4). A tile fp32 128x32 (8 granules/row, row&7
// XOR swizzle = the R4/R5-proven geometry); B tile bf16 256x32 (4 granules,
// row&3 swizzle). In-register cvt_pk to bf16 fragments (RNE).
// LDS 70 KB -> 2 blocks/CU.
// ---------------------------------------------------------------------------
__global__ __launch_bounds__(512, 4) void gemmL0(
    const float* __restrict__ X, const u16* __restrict__ W,
    const float* __restrict__ bias, u16* __restrict__ out)
{
  __shared__ __align__(16) u16 SMEM[35840];   // 70 KB (epilogue high-water)
  u16* const Af0 = SMEM;          // 128x32 fp32 = 8192 u16-units (16 KB)
  u16* const Af1 = SMEM + 8192;
  u16* const Bb0 = SMEM + 16384;  // 256x32 bf16 = 8192 u16 (16 KB)
  u16* const Bb1 = SMEM + 24576;

  const int cpx = gridDim.x >> 3;           // bijective XCD swizzle (3072%8==0)
  const int swz = (blockIdx.x & 7) * cpx + (blockIdx.x >> 3);
  const int bm = swz / 6;
  const int bn = swz - bm * 6;
  const int tid = threadIdx.x;
  const int lane = tid & 63;
  const int w = tid >> 6;
  const int wm = w >> 2, wn = w & 3;
  const int laneM = lane & 15, laneHi = lane >> 4;
  const long mRow0 = (long)bm * 128;
  const int  nRow0 = bn * 256;

  // A staging (fp32): granule idx = c*512+tid; row = idx>>3, pg = idx&7.
  // Pre-swizzled SOURCE column (rule 21): logical g = pg ^ (row&7).
  const int aR = tid >> 3;                              // 0..63 (+64 for c=1)
  const int aCol = ((tid & 7) ^ (aR & 7)) * 4;          // fp32 elems
  const float* const aS = X + (mRow0 + aR) * DD + aCol;
  // B staging (bf16): idx = c*512+tid; row = idx>>2, pg = idx&3.
  const int bR = tid >> 2;                              // 0..127 (+128 c=1)
  const int bCol = ((tid & 3) ^ (bR & 3)) * 8;          // u16 elems
  const u16* const bS = W + (long)(nRow0 + bR) * DD + bCol;

#define STAGE0(kt, afu, bbu)                                                \
  gload_lds16(aS + (kt) * 32,            (afu) + (w * 64) * 8);             \
  gload_lds16(aS + (kt) * 32 + 64 * DD,  (afu) + (512 + w * 64) * 8);       \
  gload_lds16(bS + (kt) * 32,            (bbu) + (w * 64) * 8);             \
  gload_lds16(bS + (kt) * 32 + 128 * DD, (bbu) + (512 + w * 64) * 8);

  f32x4 acc[4][4] = {};
  const int aSwz0 = (2 * laneHi) ^ (laneM & 7);   // fp32 granule (4 floats)
  const int bSwz  = laneHi ^ (laneM & 3);         // bf16 granule (8 u16)

  STAGE0(0, Af0, Bb0);
  asm volatile("s_waitcnt vmcnt(0)" ::: "memory");
  __builtin_amdgcn_sched_barrier(0);
  BAR();

#pragma unroll
  for (int kt = 0; kt < 16; ++kt) {
    const u16* const Afu = (kt & 1) ? Af1 : Af0;
    const u16* const Bbu = (kt & 1) ? Bb1 : Bb0;
    u16* const AfuN = (kt & 1) ? Af0 : Af1;
    u16* const BbuN = (kt & 1) ? Bb0 : Bb1;

    if (kt < 15) {
      STAGE0(kt + 1, AfuN, BbuN);
      asm volatile("s_waitcnt vmcnt(4)" ::: "memory");  // kt fully landed
    } else {
      asm volatile("s_waitcnt vmcnt(0)" ::: "memory");
    }
    __builtin_amdgcn_sched_barrier(0);
    BAR();

    const float* const Afl = reinterpret_cast<const float*>(Afu);
    bf16x8 a[4], b[4];
#pragma unroll
    for (int q = 0; q < 4; ++q) {
      const int r = wm * 64 + q * 16 + laneM;
      f32x4 a0 = *reinterpret_cast<const f32x4*>(&Afl[r * 32 + aSwz0 * 4]);
      f32x4 a1 = *reinterpret_cast<const f32x4*>(&Afl[r * 32 + (aSwz0 ^ 1) * 4]);
      union { unsigned u[4]; bf16x8 v; } cv;
      cv.u[0] = cvtpk_bf16(a0[0], a0[1]);
      cv.u[1] = cvtpk_bf16(a0[2], a0[3]);
      cv.u[2] = cvtpk_bf16(a1[0], a1[1]);
      cv.u[3] = cvtpk_bf16(a1[2], a1[3]);
      a[q] = cv.v;
    }
#pragma unroll
    for (int q = 0; q < 4; ++q) {
      const int r = wn * 64 + q * 16 + laneM;
      b[q] = *reinterpret_cast<const bf16x8*>(&Bbu[r * 32 + bSwz * 8]);
    }

    __builtin_amdgcn_s_setprio(1);
#pragma unroll
    for (int q = 0; q < 4; ++q)
#pragma unroll
      for (int r = 0; r < 4; ++r)
        acc[q][r] = __builtin_amdgcn_mfma_f32_16x16x32_bf16(
            a[q], b[r], acc[q][r], 0, 0, 0);
    __builtin_amdgcn_s_setprio(0);
    BAR();
  }
#undef STAGE0

  gemm_epilogue(SMEM, acc, bias, mRow0, nRow0, tid, wm, wn, laneM, laneHi, out);
}

// ---------------------------------------------------------------------------
// Layer-1 GEMM: A bf16 (from phase3's xb). Same tile; TRIPLE-buffered
// depth-2 prefetch with counted vmcnt(6) (2 phases of latency coverage).
// Both tiles XOR-swizzled (row&3, 4 granules/row). LDS 72 KB -> 2 blocks/CU.
// ---------------------------------------------------------------------------
__global__ __launch_bounds__(512, 4) void gemmL1(
    const u16* __restrict__ A, const u16* __restrict__ W,
    const float* __restrict__ bias, u16* __restrict__ out)
{
  __shared__ __align__(16) u16 SMEM[36864];   // 72 KB
  u16* const Ab[3] = {SMEM, SMEM + 4096, SMEM + 8192};          // 128x32 each
  u16* const Bb[3] = {SMEM + 12288, SMEM + 20480, SMEM + 28672}; // 256x32 each

  const int cpx = gridDim.x >> 3;
  const int swz = (blockIdx.x & 7) * cpx + (blockIdx.x >> 3);
  const int bm = swz / 6;
  const int bn = swz - bm * 6;
  const int tid = threadIdx.x;
  const int lane = tid & 63;
  const int w = tid >> 6;
  const int wm = w >> 2, wn = w & 3;
  const int laneM = lane & 15, laneHi = lane >> 4;
  const long mRow0 = (long)bm * 128;
  const int  nRow0 = bn * 256;

  // A staging: 512 granules, one call: row = tid>>2, pg = tid&3.
  const int aR = tid >> 2;
  const int aCol = ((tid & 3) ^ (aR & 3)) * 8;
  const u16* const aS = A + (mRow0 + aR) * DD + aCol;
  // B staging: 1024 granules, two calls.
  const int bR = tid >> 2;
  const int bCol = ((tid & 3) ^ (bR & 3)) * 8;
  const u16* const bS = W + (long)(nRow0 + bR) * DD + bCol;

#define STAGE1(kt, abu, bbu)                                                \
  gload_lds16(aS + (kt) * 32,            (abu) + w * 512);                  \
  gload_lds16(bS + (kt) * 32,            (bbu) + (w * 64) * 8);             \
  gload_lds16(bS + (kt) * 32 + 128 * DD, (bbu) + (512 + w * 64) * 8);

  f32x4 acc[4][4] = {};
  const int abSwz = laneHi ^ (laneM & 3);

  STAGE1(0, Ab[0], Bb[0]);
  STAGE1(1, Ab[1], Bb[1]);
  asm volatile("s_waitcnt vmcnt(3)" ::: "memory");   // kt0 landed
  __builtin_amdgcn_sched_barrier(0);
  BAR();

#pragma unroll
  for (int kt = 0; kt < 16; ++kt) {
    const u16* const Abu = Ab[kt % 3];
    const u16* const Bbu = Bb[kt % 3];

    if (kt < 14) {
      STAGE1(kt + 2, Ab[(kt + 2) % 3], Bb[(kt + 2) % 3]);
      asm volatile("s_waitcnt vmcnt(6)" ::: "memory");  // kt landed (oldest)
    } else if (kt == 14) {
      asm volatile("s_waitcnt vmcnt(3)" ::: "memory");
    } else {
      asm volatile("s_waitcnt vmcnt(0)" ::: "memory");
    }
    __builtin_amdgcn_sched_barrier(0);
    BAR();

    bf16x8 a[4], b[4];
#pragma unroll
    for (int q = 0; q < 4; ++q) {
      const int ra = wm * 64 + q * 16 + laneM;
      a[q] = *reinterpret_cast<const bf16x8*>(&Abu[ra * 32 + abSwz * 8]);
      const int rb = wn * 64 + q * 16 + laneM;
      b[q] = *reinterpret_cast<const bf16x8*>(&Bbu[rb * 32 + abSwz * 8]);
    }

    __builtin_amdgcn_s_setprio(1);
#pragma unroll
    for (int q = 0; q < 4; ++q)
#pragma unroll
      for (int r = 0; r < 4; ++r)
        acc[q][r] = __builtin_amdgcn_mfma_f32_16x16x32_bf16(
            a[q], b[r], acc[q][r], 0, 0, 0);
    __builtin_amdgcn_s_setprio(0);
    BAR();
  }
#undef STAGE1

  gemm_epilogue(SMEM, acc, bias, mRow0, nRow0, tid, wm, wn, laneM, laneHi, out);
}

// ---------------------------------------------------------------------------
// Chunked parallel scan; 4 h-chains per thread (8B vector loads),
// 131072 threads. (unchanged from R5/R7, validated)
// ---------------------------------------------------------------------------
__global__ __launch_bounds__(256) void scan_phase1(
    const u16* __restrict__ gates,
    float* __restrict__ Aout, float* __restrict__ Bout)
{
  const int tid = blockIdx.x * 256 + threadIdx.x;   // 0..131071
  const int cg = tid & 2047;
  const int k  = tid >> 11;
  const int b  = cg >> 7;
  const int h4 = cg & 127;
  const int chain = b * 512 + h4 * 4;

  const u16* g = gates + ((size_t)b * TT + (size_t)k * CS) * NG + h4 * 4;

  float Ac[4], Bc[4];
#pragma unroll
  for (int j = 0; j < 4; ++j) { Ac[j] = 1.f; Bc[j] = 0.f; }

  for (int t = 0; t < CS; t += 4) {
    u16x4 zv[4], fv[4];
#pragma unroll
    for (int u = 0; u < 4; ++u) {
      const u16* gt = g + (size_t)(t + u) * NG;
      zv[u] = *reinterpret_cast<const u16x4*>(gt);
      fv[u] = *reinterpret_cast<const u16x4*>(gt + 512);
    }
#pragma unroll
    for (int u = 0; u < 4; ++u)
#pragma unroll
      for (int j = 0; j < 4; ++j) {
        float z = bf2f(zv[u][j]); z = z > 0.f ? z : 0.f;
        const float f = sigm(bf2f(fv[u][j]));
        Ac[j] = f * Ac[j];
        Bc[j] = f * Bc[j] + (1.f - f) * z;
      }
  }
#pragma unroll
  for (int j = 0; j < 4; ++j) {
    Aout[(size_t)k * NCHAIN + chain + j] = Ac[j];
    Bout[(size_t)k * NCHAIN + chain + j] = Bc[j];
  }
}

__global__ __launch_bounds__(256) void scan_phase2(
    const float* __restrict__ Ain, const float* __restrict__ Bin,
    const float* __restrict__ h0, const int layer,
    float* __restrict__ cstart, float* __restrict__ hout)
{
  const int chain = blockIdx.x * 256 + threadIdx.x;  // 0..8191
  const int b = chain >> 9;
  const int h = chain & 511;

  float c = h0[b * 1024 + layer * 512 + h];
#pragma unroll 8
  for (int k = 0; k < NCH; ++k) {
    cstart[(size_t)k * NCHAIN + chain] = c;
    c = Ain[(size_t)k * NCHAIN + chain] * c + Bin[(size_t)k * NCHAIN + chain];
  }
  hout[b * 1024 + layer * 512 + h] = c;
}

// MODE 0: layer 0 -> write bf16 xb only. MODE 1: layer 1 -> write fp32 x.
template <int MODE>
__global__ __launch_bounds__(256) void scan_phase3(
    const u16* __restrict__ gates, const float* __restrict__ cstart,
    float* __restrict__ xout, u16* __restrict__ xb)
{
  const int tid = blockIdx.x * 256 + threadIdx.x;
  const int cg = tid & 2047;
  const int k  = tid >> 11;
  const int b  = cg >> 7;
  const int h4 = cg & 127;
  const int chain = b * 512 + h4 * 4;

  const u16* g = gates + ((size_t)b * TT + (size_t)k * CS) * NG + h4 * 4;
  const size_t xrow0 = ((size_t)b * TT + (size_t)k * CS) * DD + h4 * 4;

  float c[4];
#pragma unroll
  for (int j = 0; j < 4; ++j) c[j] = cstart[(size_t)k * NCHAIN + chain + j];

  for (int t = 0; t < CS; t += 4) {
    u16x4 zv[4], fv[4], ov[4];
#pragma unroll
    for (int u = 0; u < 4; ++u) {
      const u16* gt = g + (size_t)(t + u) * NG;
      zv[u] = *reinterpret_cast<const u16x4*>(gt);
      fv[u] = *reinterpret_cast<const u16x4*>(gt + 512);
      ov[u] = *reinterpret_cast<const u16x4*>(gt + 1024);
    }
#pragma unroll
    for (int u = 0; u < 4; ++u) {
      float xv[4];
#pragma unroll
      for (int j = 0; j < 4; ++j) {
        float z = bf2f(zv[u][j]); z = z > 0.f ? z : 0.f;
        const float f = sigm(bf2f(fv[u][j]));
        const float o = sigm(bf2f(ov[u][j]));
        c[j] = f * c[j] + (1.f - f) * z;
        xv[j] = o * c[j];
      }
      if (MODE == 0) {
        u16x4 pk;
#pragma unroll
        for (int j = 0; j < 4; ++j) pk[j] = f2bf(xv[j]);
        *reinterpret_cast<u16x4*>(xb + xrow0 + (size_t)(t + u) * DD) = pk;
      } else {
        *reinterpret_cast<float4*>(xout + xrow0 + (size_t)(t + u) * DD) =
            make_float4(xv[0], xv[1], xv[2], xv[3]);
      }
    }
  }
}

extern "C" void kernel_launch(void* const* d_in, const int* in_sizes, int n_in,
                              void* d_out, int out_size, void* d_ws, size_t ws_size,
                              hipStream_t stream) {
  const float* x  = (const float*)d_in[0];
  const float* h0 = (const float*)d_in[1];
  const float* W0 = (const float*)d_in[2];
  const float* b0 = (const float*)d_in[3];
  const float* W1 = (const float*)d_in[4];
  const float* b1 = (const float*)d_in[5];

  float* out_x = (float*)d_out;                       // [B*T, 512]
  float* out_h = out_x + (size_t)BB * TT * DD;        // [B, 2, 512]

  // workspace layout (~278 MB)
  char* ws = (char*)d_ws;
  u16* gates = (u16*)ws;                              // bf16 [B*T,1536] 201.3MB
  size_t off = (size_t)BB * TT * NG * 2;
  u16* xb  = (u16*)(ws + off);                        // bf16 [B*T,512]  67.1MB
  off += (size_t)BB * TT * DD * 2;
  u16* W0b = (u16*)(ws + off); off += (size_t)NG * DD * 2;
  u16* W1b = (u16*)(ws + off); off += (size_t)NG * DD * 2;
  float* Abuf   = (float*)(ws + off); off += (size_t)NCH * NCHAIN * 4;
  float* Bbuf   = (float*)(ws + off); off += (size_t)NCH * NCHAIN * 4;
  float* cstart = (float*)(ws + off);

  dim3 blk(256);
  dim3 gemmGrid((NG / 256) * ((BB * TT) / 128));      // 6*512 = 3072
  dim3 gemmBlk(512);
  dim3 pGrid((NCHAIN / 4 * NCH) / 256);               // 512 blocks
  dim3 p2Grid(NCHAIN / 256);                          // 32

  // only the tiny W converts remain (x is consumed fp32 by gemmL0)
  f32_to_bf16<<<384, blk, 0, stream>>>(W0, W0b, (long)NG * DD);
  f32_to_bf16<<<384, blk, 0, stream>>>(W1, W1b, (long)NG * DD);

  // Layer 0
  gemmL0<<<gemmGrid, gemmBlk, 0, stream>>>(x, W0b, b0, gates);
  scan_phase1<<<pGrid, blk, 0, stream>>>(gates, Abuf, Bbuf);
  scan_phase2<<<p2Grid, blk, 0, stream>>>(Abuf, Bbuf, h0, 0, cstart, out_h);
  scan_phase3<0><<<pGrid, blk, 0, stream>>>(gates, cstart, out_x, xb);
  // Layer 1 (xb written by phase3, consumed by gemmL1)
  gemmL1<<<gemmGrid, gemmBlk, 0, stream>>>(xb, W1b, b1, gates);
  scan_phase1<<<pGrid, blk, 0, stream>>>(gates, Abuf, Bbuf);
  scan_phase2<<<p2Grid, blk, 0, stream>>>(Abuf, Bbuf, h0, 1, cstart, out_h);
  scan_phase3<1><<<pGrid, blk, 0, stream>>>(gates, cstart, out_x, nullptr);
}

// Round 9
// 468.197 us; speedup vs baseline: 1.0361x; 1.0361x over previous
//
#include <hip/hip_runtime.h>
#include <cstdint>
#include <cstddef>

// Problem constants: B=16, T=4096, D_IN=H=512, L=2, 3H=1536
#define BB 16
#define TT 4096
#define DD 512
#define NG 1536
#define NCH 128           // chunks per chain
#define CS  (TT / NCH)    // 32 timesteps per chunk
#define NCHAIN (BB * DD)  // 8192 chains

typedef __bf16 bf16x8 __attribute__((ext_vector_type(8)));
typedef float f32x4 __attribute__((ext_vector_type(4)));
typedef unsigned short u16;
typedef __attribute__((ext_vector_type(4))) unsigned short u16x4;

__device__ __forceinline__ u16 f2bf(float f) {
  union { float f; unsigned u; } v; v.f = f;
  return (u16)((v.u + 0x7FFFu + ((v.u >> 16) & 1u)) >> 16);
}
__device__ __forceinline__ float bf2f(u16 s) {
  union { unsigned u; float f; } v; v.u = ((unsigned)s) << 16;
  return v.f;
}
__device__ __forceinline__ float sigm(float x) {
  return 1.f / (1.f + __expf(-x));
}

// async global->LDS, 16B per lane. LDS dest = wave-uniform base + lane*16.
__device__ __forceinline__ void gload_lds16(const void* g, void* l) {
  __builtin_amdgcn_global_load_lds(
      (const __attribute__((address_space(1))) unsigned*)g,
      (__attribute__((address_space(3))) unsigned*)l, 16, 0, 0);
}

#define BAR() __builtin_amdgcn_s_barrier()

// ---------------------------------------------------------------------------
// fp32 -> bf16 bulk convert (x: 67 MB out; W0/W1: 1.5 MB each)
// ---------------------------------------------------------------------------
__global__ __launch_bounds__(256) void f32_to_bf16(
    const float* __restrict__ in, u16* __restrict__ out, long n)
{
  const long stride = (long)gridDim.x * 256 * 8;
  for (long i = ((long)blockIdx.x * 256 + threadIdx.x) * 8; i < n; i += stride) {
    float4 a = *reinterpret_cast<const float4*>(in + i);
    float4 b = *reinterpret_cast<const float4*>(in + i + 4);
    uint4 p;
    p.x = (unsigned)f2bf(a.x) | ((unsigned)f2bf(a.y) << 16);
    p.y = (unsigned)f2bf(a.z) | ((unsigned)f2bf(a.w) << 16);
    p.z = (unsigned)f2bf(b.x) | ((unsigned)f2bf(b.y) << 16);
    p.w = (unsigned)f2bf(b.z) | ((unsigned)f2bf(b.w) << 16);
    *reinterpret_cast<uint4*>(out + i) = p;
  }
}

// ---------------------------------------------------------------------------
// GEMM (R8's validated gemmL1, now both layers): gates[m][n] = bias[n] +
// sum_k A[m][k]*W[n][k]; A,W bf16 ld=512. 128x256 tile, BK=32, 8 waves of
// 64x64 (acc=64 VGPR -> 2 blocks/CU). TRIPLE-buffered depth-2 prefetch,
// counted vmcnt(6): at iter kt outstanding = S(kt),S(kt+1),S(kt+2) -> wait
// retires exactly S(kt). XOR-swizzled LDS (row&3 on 16B granules),
// pre-swizzled global source (rule 21). LDS 72 KB.
// ---------------------------------------------------------------------------
__global__ __launch_bounds__(512, 4) void gemmB(
    const u16* __restrict__ A, const u16* __restrict__ W,
    const float* __restrict__ bias, u16* __restrict__ out)
{
  __shared__ __align__(16) u16 SMEM[36864];   // 72 KB
  u16* const Ab[3] = {SMEM, SMEM + 4096, SMEM + 8192};           // 128x32
  u16* const Bb[3] = {SMEM + 12288, SMEM + 20480, SMEM + 28672}; // 256x32

  const int cpx = gridDim.x >> 3;          // bijective XCD swizzle (3072%8==0)
  const int swz = (blockIdx.x & 7) * cpx + (blockIdx.x >> 3);
  const int bm = swz / 6;
  const int bn = swz - bm * 6;
  const int tid = threadIdx.x;
  const int lane = tid & 63;
  const int w = tid >> 6;
  const int wm = w >> 2, wn = w & 3;
  const int laneM = lane & 15, laneHi = lane >> 4;
  const long mRow0 = (long)bm * 128;
  const int  nRow0 = bn * 256;

  // staging: granule idx = tid (A) / c*512+tid (B); row = idx>>2, pg = idx&3.
  const int aR = tid >> 2;
  const int aCol = ((tid & 3) ^ (aR & 3)) * 8;     // pre-swizzled source col
  const u16* const aS = A + (mRow0 + aR) * DD + aCol;
  const int bR = tid >> 2;
  const int bCol = ((tid & 3) ^ (bR & 3)) * 8;
  const u16* const bS = W + (long)(nRow0 + bR) * DD + bCol;

#define STAGE(kt, abu, bbu)                                                 \
  gload_lds16(aS + (kt) * 32,            (abu) + w * 512);                  \
  gload_lds16(bS + (kt) * 32,            (bbu) + (w * 64) * 8);             \
  gload_lds16(bS + (kt) * 32 + 128 * DD, (bbu) + (512 + w * 64) * 8);

  f32x4 acc[4][4] = {};
  const int abSwz = laneHi ^ (laneM & 3);

  STAGE(0, Ab[0], Bb[0]);
  STAGE(1, Ab[1], Bb[1]);
  asm volatile("s_waitcnt vmcnt(3)" ::: "memory");   // S0 landed
  __builtin_amdgcn_sched_barrier(0);
  BAR();

#pragma unroll
  for (int kt = 0; kt < 16; ++kt) {
    const u16* const Abu = Ab[kt % 3];
    const u16* const Bbu = Bb[kt % 3];

    if (kt < 14) {
      STAGE(kt + 2, Ab[(kt + 2) % 3], Bb[(kt + 2) % 3]);
      asm volatile("s_waitcnt vmcnt(6)" ::: "memory");  // S(kt) retired
    } else if (kt == 14) {
      asm volatile("s_waitcnt vmcnt(3)" ::: "memory");  // S14 retired
    } else {
      asm volatile("s_waitcnt vmcnt(0)" ::: "memory");  // S15 retired
    }
    __builtin_amdgcn_sched_barrier(0);
    BAR();

    bf16x8 a[4], b[4];
#pragma unroll
    for (int q = 0; q < 4; ++q) {
      const int ra = wm * 64 + q * 16 + laneM;
      a[q] = *reinterpret_cast<const bf16x8*>(&Abu[ra * 32 + abSwz * 8]);
      const int rb = wn * 64 + q * 16 + laneM;
      b[q] = *reinterpret_cast<const bf16x8*>(&Bbu[rb * 32 + abSwz * 8]);
    }

    __builtin_amdgcn_s_setprio(1);
#pragma unroll
    for (int q = 0; q < 4; ++q)
#pragma unroll
      for (int r = 0; r < 4; ++r)
        acc[q][r] = __builtin_amdgcn_mfma_f32_16x16x32_bf16(
            a[q], b[r], acc[q][r], 0, 0, 0);
    __builtin_amdgcn_s_setprio(0);
    BAR();
  }
#undef STAGE

  // ---- epilogue: LDS bounce (EPS=280), coalesced 16B/lane stores
  // (validated R5/R7/R8: WRITE_SIZE == 196.6 MB ideal).
  float bvv[4];
#pragma unroll
  for (int ni = 0; ni < 4; ++ni)
    bvv[ni] = bias[nRow0 + wn * 64 + ni * 16 + laneM];
  u16* const ep = SMEM;
#pragma unroll
  for (int mi = 0; mi < 4; ++mi)
#pragma unroll
    for (int ni = 0; ni < 4; ++ni)
#pragma unroll
      for (int r = 0; r < 4; ++r)
        ep[(wm * 64 + mi * 16 + laneHi * 4 + r) * 280 +
           wn * 64 + ni * 16 + laneM] = f2bf(acc[mi][ni][r] + bvv[ni]);
  asm volatile("s_waitcnt lgkmcnt(0)" ::: "memory");
  __builtin_amdgcn_sched_barrier(0);
  BAR();
#pragma unroll
  for (int it = 0; it < 8; ++it) {
    const int row = tid >> 2;
    const int col = ((tid & 3) + it * 4) * 8;
    uint4 v = *reinterpret_cast<const uint4*>(&ep[row * 280 + col]);
    *reinterpret_cast<uint4*>(
        &out[(mRow0 + row) * (long)NG + nRow0 + col]) = v;
  }
}

// ---------------------------------------------------------------------------
// Chunked parallel scan; 4 h-chains per thread, NCH=128 (CS=32) ->
// 262144 threads = 16 waves/CU for phases 1/3.
// ---------------------------------------------------------------------------
__global__ __launch_bounds__(256) void scan_phase1(
    const u16* __restrict__ gates,
    float* __restrict__ Aout, float* __restrict__ Bout)
{
  const int tid = blockIdx.x * 256 + threadIdx.x;   // 0..262143
  const int cg = tid & 2047;
  const int k  = tid >> 11;
  const int b  = cg >> 7;
  const int h4 = cg & 127;
  const int chain = b * 512 + h4 * 4;

  const u16* g = gates + ((size_t)b * TT + (size_t)k * CS) * NG + h4 * 4;

  float Ac[4], Bc[4];
#pragma unroll
  for (int j = 0; j < 4; ++j) { Ac[j] = 1.f; Bc[j] = 0.f; }

  for (int t = 0; t < CS; t += 4) {
    u16x4 zv[4], fv[4];
#pragma unroll
    for (int u = 0; u < 4; ++u) {
      const u16* gt = g + (size_t)(t + u) * NG;
      zv[u] = *reinterpret_cast<const u16x4*>(gt);
      fv[u] = *reinterpret_cast<const u16x4*>(gt + 512);
    }
#pragma unroll
    for (int u = 0; u < 4; ++u)
#pragma unroll
      for (int j = 0; j < 4; ++j) {
        float z = bf2f(zv[u][j]); z = z > 0.f ? z : 0.f;
        const float f = sigm(bf2f(fv[u][j]));
        Ac[j] = f * Ac[j];
        Bc[j] = f * Bc[j] + (1.f - f) * z;
      }
  }
#pragma unroll
  for (int j = 0; j < 4; ++j) {
    Aout[(size_t)k * NCHAIN + chain + j] = Ac[j];
    Bout[(size_t)k * NCHAIN + chain + j] = Bc[j];
  }
}

__global__ __launch_bounds__(256) void scan_phase2(
    const float* __restrict__ Ain, const float* __restrict__ Bin,
    const float* __restrict__ h0, const int layer,
    float* __restrict__ cstart, float* __restrict__ hout)
{
  const int chain = blockIdx.x * 256 + threadIdx.x;  // 0..8191
  const int b = chain >> 9;
  const int h = chain & 511;

  float c = h0[b * 1024 + layer * 512 + h];
#pragma unroll 8
  for (int k = 0; k < NCH; ++k) {
    cstart[(size_t)k * NCHAIN + chain] = c;
    c = Ain[(size_t)k * NCHAIN + chain] * c + Bin[(size_t)k * NCHAIN + chain];
  }
  hout[b * 1024 + layer * 512 + h] = c;
}

// MODE 0: layer 0 -> write bf16 xb only. MODE 1: layer 1 -> write fp32 x.
template <int MODE>
__global__ __launch_bounds__(256) void scan_phase3(
    const u16* __restrict__ gates, const float* __restrict__ cstart,
    float* __restrict__ xout, u16* __restrict__ xb)
{
  const int tid = blockIdx.x * 256 + threadIdx.x;
  const int cg = tid & 2047;
  const int k  = tid >> 11;
  const int b  = cg >> 7;
  const int h4 = cg & 127;
  const int chain = b * 512 + h4 * 4;

  const u16* g = gates + ((size_t)b * TT + (size_t)k * CS) * NG + h4 * 4;
  const size_t xrow0 = ((size_t)b * TT + (size_t)k * CS) * DD + h4 * 4;

  float c[4];
#pragma unroll
  for (int j = 0; j < 4; ++j) c[j] = cstart[(size_t)k * NCHAIN + chain + j];

  for (int t = 0; t < CS; t += 4) {
    u16x4 zv[4], fv[4], ov[4];
#pragma unroll
    for (int u = 0; u < 4; ++u) {
      const u16* gt = g + (size_t)(t + u) * NG;
      zv[u] = *reinterpret_cast<const u16x4*>(gt);
      fv[u] = *reinterpret_cast<const u16x4*>(gt + 512);
      ov[u] = *reinterpret_cast<const u16x4*>(gt + 1024);
    }
#pragma unroll
    for (int u = 0; u < 4; ++u) {
      float xv[4];
#pragma unroll
      for (int j = 0; j < 4; ++j) {
        float z = bf2f(zv[u][j]); z = z > 0.f ? z : 0.f;
        const float f = sigm(bf2f(fv[u][j]));
        const float o = sigm(bf2f(ov[u][j]));
        c[j] = f * c[j] + (1.f - f) * z;
        xv[j] = o * c[j];
      }
      if (MODE == 0) {
        u16x4 pk;
#pragma unroll
        for (int j = 0; j < 4; ++j) pk[j] = f2bf(xv[j]);
        *reinterpret_cast<u16x4*>(xb + xrow0 + (size_t)(t + u) * DD) = pk;
      } else {
        *reinterpret_cast<float4*>(xout + xrow0 + (size_t)(t + u) * DD) =
            make_float4(xv[0], xv[1], xv[2], xv[3]);
      }
    }
  }
}

extern "C" void kernel_launch(void* const* d_in, const int* in_sizes, int n_in,
                              void* d_out, int out_size, void* d_ws, size_t ws_size,
                              hipStream_t stream) {
  const float* x  = (const float*)d_in[0];
  const float* h0 = (const float*)d_in[1];
  const float* W0 = (const float*)d_in[2];
  const float* b0 = (const float*)d_in[3];
  const float* W1 = (const float*)d_in[4];
  const float* b1 = (const float*)d_in[5];

  float* out_x = (float*)d_out;                       // [B*T, 512]
  float* out_h = out_x + (size_t)BB * TT * DD;        // [B, 2, 512]

  // workspace layout (~284 MB)
  char* ws = (char*)d_ws;
  u16* gates = (u16*)ws;                              // bf16 [B*T,1536] 201.3MB
  size_t off = (size_t)BB * TT * NG * 2;
  u16* xb  = (u16*)(ws + off);                        // bf16 [B*T,512]  67.1MB
  off += (size_t)BB * TT * DD * 2;
  u16* W0b = (u16*)(ws + off); off += (size_t)NG * DD * 2;
  u16* W1b = (u16*)(ws + off); off += (size_t)NG * DD * 2;
  float* Abuf   = (float*)(ws + off); off += (size_t)NCH * NCHAIN * 4; // 4MB
  float* Bbuf   = (float*)(ws + off); off += (size_t)NCH * NCHAIN * 4; // 4MB
  float* cstart = (float*)(ws + off);                                   // 4MB

  dim3 blk(256);
  dim3 gemmGrid((NG / 256) * ((BB * TT) / 128));      // 6*512 = 3072
  dim3 gemmBlk(512);
  dim3 pGrid((NCHAIN / 4 * NCH) / 256);               // 1024 blocks
  dim3 p2Grid(NCHAIN / 256);                          // 32

  f32_to_bf16<<<2048, blk, 0, stream>>>(x, xb, (long)BB * TT * DD);
  f32_to_bf16<<<384, blk, 0, stream>>>(W0, W0b, (long)NG * DD);
  f32_to_bf16<<<384, blk, 0, stream>>>(W1, W1b, (long)NG * DD);

  // Layer 0
  gemmB<<<gemmGrid, gemmBlk, 0, stream>>>(xb, W0b, b0, gates);
  scan_phase1<<<pGrid, blk, 0, stream>>>(gates, Abuf, Bbuf);
  scan_phase2<<<p2Grid, blk, 0, stream>>>(Abuf, Bbuf, h0, 0, cstart, out_h);
  scan_phase3<0><<<pGrid, blk, 0, stream>>>(gates, cstart, out_x, xb);
  // Layer 1 (xb rewritten by phase3 only after gemm0 consumed it)
  gemmB<<<gemmGrid, gemmBlk, 0, stream>>>(xb, W1b, b1, gates);
  scan_phase1<<<pGrid, blk, 0, stream>>>(gates, Abuf, Bbuf);
  scan_phase2<<<p2Grid, blk, 0, stream>>>(Abuf, Bbuf, h0, 1, cstart, out_h);
  scan_phase3<1><<<pGrid, blk, 0, stream>>>(gates, cstart, out_x, nullptr);
}